// Round 1
// baseline (144.438 us; speedup 1.0000x reference)
//
#include <hip/hip_runtime.h>
#include <hip/hip_bf16.h>

#define N_NODES  50000
#define N_EDGES  300000
#define IN_FEATS 1433
#define HIDDEN   16
#define OUT_F    7
#define KPAD     1472   // 23*64, zero-padded K extent for W1 in LDS
#define WROW     9      // dwords per W1 row in LDS (8 used = 16 bf16, +1 pad -> conflict-free)

__device__ __forceinline__ unsigned short f2bf(float f) {
    unsigned int x = __float_as_uint(f);
    unsigned int r = x + 0x7fffu + ((x >> 16) & 1u);   // RNE
    return (unsigned short)(r >> 16);
}

// Kernel 1: H = F @ W1 (bf16 weights, fp32 features/accum); aggbuf = H + b1
__global__ __launch_bounds__(256) void k1_gemm(
    const float* __restrict__ F, const float* __restrict__ W1,
    const float* __restrict__ b1, float* __restrict__ H,
    float* __restrict__ aggbuf)
{
    __shared__ unsigned int Wl[KPAD * WROW];   // 52,992 B
    const int tid = threadIdx.x;

    // Stage W1 as packed bf16 pairs, zero-padded rows [1433, KPAD)
    for (int idx = tid; idx < KPAD * 8; idx += 256) {
        int k = idx >> 3, c = idx & 7;
        unsigned int u = 0u;
        if (k < IN_FEATS) {
            unsigned int lo = f2bf(W1[k * 16 + 2 * c]);
            unsigned int hi = f2bf(W1[k * 16 + 2 * c + 1]);
            u = lo | (hi << 16);
        }
        Wl[k * WROW + c] = u;
    }
    __syncthreads();

    const int wave = tid >> 6;
    const int lane = tid & 63;
    const float b1v = b1[lane & 15];
    const int ntiles = N_NODES / 16;   // 3125, exact

    for (int tile = blockIdx.x; tile < ntiles; tile += gridDim.x) {
        const int r0 = tile * 16 + wave * 4;           // this wave's 4 rows
        const float* fp = F + (size_t)r0 * IN_FEATS;

        float v[64];                                    // acc[idx = r*16 + j]
        #pragma unroll
        for (int i = 0; i < 64; ++i) v[i] = 0.f;

        for (int i = 0; i < KPAD / 64; ++i) {          // 23 iters
            const int k = i * 64 + lane;
            float f0 = 0.f, f1 = 0.f, f2 = 0.f, f3 = 0.f;
            if (k < IN_FEATS) {
                f0 = fp[k];
                f1 = fp[IN_FEATS + k];
                f2 = fp[2 * IN_FEATS + k];
                f3 = fp[3 * IN_FEATS + k];
            }
            float wv[16];
            #pragma unroll
            for (int c = 0; c < 8; ++c) {
                unsigned int u = Wl[k * WROW + c];
                wv[2 * c]     = __uint_as_float(u << 16);
                wv[2 * c + 1] = __uint_as_float(u & 0xffff0000u);
            }
            #pragma unroll
            for (int j = 0; j < 16; ++j) {
                v[j]      += f0 * wv[j];
                v[16 + j] += f1 * wv[j];
                v[32 + j] += f2 * wv[j];
                v[48 + j] += f3 * wv[j];
            }
        }

        // Halving butterfly: lane l ends with v[0] = full K-sum of idx = l
        #pragma unroll
        for (int d = 5; d >= 0; --d) {
            const int half = 1 << d;
            const bool hi = (lane >> d) & 1;
            #pragma unroll
            for (int t = 0; t < (1 << d); ++t) {
                float sent = hi ? v[t] : v[t + half];
                float recv = __shfl_xor(sent, half, 64);
                float keep = hi ? v[t + half] : v[t];
                v[t] = keep + recv;
            }
        }
        // idx = lane -> row r0 + (lane>>4), col lane&15 -> flat r0*16 + lane
        const size_t off = (size_t)r0 * 16 + lane;
        H[off] = v[0];
        aggbuf[off] = v[0] + b1v;                      // 256B coalesced per wave
    }
}

// Kernel 2: aggbuf[d] += H[s] over edges (layer-1 scatter-add)
__global__ __launch_bounds__(256) void k2_scatter1(
    const int* __restrict__ src, const int* __restrict__ dst,
    const float* __restrict__ H, float* __restrict__ aggbuf)
{
    int t = blockIdx.x * 256 + threadIdx.x;
    int e = t >> 4, j = t & 15;
    if (e < N_EDGES) {
        int s = src[e], d = dst[e];
        atomicAdd(&aggbuf[(size_t)d * 16 + j], H[(size_t)s * 16 + j]);
    }
}

// Kernel 3: x = relu(aggbuf); G = x @ W2; out = G + b2
__global__ __launch_bounds__(256) void k3_layer2(
    const float* __restrict__ aggbuf, const float* __restrict__ W2,
    const float* __restrict__ b2, float* __restrict__ G,
    float* __restrict__ out)
{
    int n = blockIdx.x * 256 + threadIdx.x;
    if (n >= N_NODES) return;
    const float* a = aggbuf + (size_t)n * 16;
    float x[16];
    #pragma unroll
    for (int k = 0; k < 16; ++k) { float vv = a[k]; x[k] = vv > 0.f ? vv : 0.f; }
    #pragma unroll
    for (int j = 0; j < OUT_F; ++j) {
        float g = 0.f;
        #pragma unroll
        for (int k = 0; k < 16; ++k) g += x[k] * W2[k * OUT_F + j];
        G[(size_t)n * OUT_F + j] = g;
        out[(size_t)n * OUT_F + j] = g + b2[j];
    }
}

// Kernel 4: out[d] += G[s] over edges (layer-2 scatter-add)
__global__ __launch_bounds__(256) void k4_scatter2(
    const int* __restrict__ src, const int* __restrict__ dst,
    const float* __restrict__ G, float* __restrict__ out)
{
    int t = blockIdx.x * 256 + threadIdx.x;
    int e = t / OUT_F, j = t % OUT_F;
    if (e < N_EDGES) {
        atomicAdd(&out[(size_t)dst[e] * OUT_F + j], G[(size_t)src[e] * OUT_F + j]);
    }
}

extern "C" void kernel_launch(void* const* d_in, const int* in_sizes, int n_in,
                              void* d_out, int out_size, void* d_ws, size_t ws_size,
                              hipStream_t stream)
{
    const float* F  = (const float*)d_in[0];
    const int*   src = (const int*)d_in[1];
    const int*   dst = (const int*)d_in[2];
    const float* W1 = (const float*)d_in[3];
    const float* b1 = (const float*)d_in[4];
    const float* W2 = (const float*)d_in[5];
    const float* b2 = (const float*)d_in[6];
    float* out = (float*)d_out;

    float* H      = (float*)d_ws;                         // 800,000 f32
    float* aggbuf = H + (size_t)N_NODES * HIDDEN;         // 800,000 f32
    float* G      = H;                                    // reuse H after k2 (dead)

    // k1: 768 blocks = 3 blocks/CU (LDS-capped), grid-stride over 3125 row tiles
    k1_gemm<<<768, 256, 0, stream>>>(F, W1, b1, H, aggbuf);
    k2_scatter1<<<(N_EDGES * 16) / 256, 256, 0, stream>>>(src, dst, H, aggbuf);
    k3_layer2<<<(N_NODES + 255) / 256, 256, 0, stream>>>(aggbuf, W2, b2, G, out);
    k4_scatter2<<<(N_EDGES * OUT_F + 255) / 256, 256, 0, stream>>>(src, dst, G, out);
}

// Round 2
// 118.738 us; speedup vs baseline: 1.2164x; 1.2164x over previous
//
#include <hip/hip_runtime.h>
#include <hip/hip_bf16.h>

#define N_NODES  50000
#define N_EDGES  300000
#define IN_FEATS 1433
#define HIDDEN   16
#define OUT_F    7
#define KPAD     1472   // 23*64, zero-padded K extent for W1 in LDS
#define WROW     9      // dwords per W1 row in LDS (8 used = 16 bf16, +1 pad -> conflict-free)

__device__ __forceinline__ unsigned short f2bf(float f) {
    unsigned int x = __float_as_uint(f);
    unsigned int r = x + 0x7fffu + ((x >> 16) & 1u);   // RNE
    return (unsigned short)(r >> 16);
}

// Kernel 1: H = F @ W1 (bf16 weights, fp32 features/accum); aggbuf = H + b1
// Work unit: one wave owns 4 consecutive rows; 12500 chunks grid-strided by
// gridDim*4 waves (granularity ~2.7us, was ~11us/block-tile -> tail imbalance).
__global__ __launch_bounds__(256) void k1_gemm(
    const float* __restrict__ F, const float* __restrict__ W1,
    const float* __restrict__ b1, float* __restrict__ H,
    float* __restrict__ aggbuf)
{
    __shared__ unsigned int Wl[KPAD * WROW];   // 52,992 B -> 3 blocks/CU
    const int tid = threadIdx.x;

    // Stage W1 as packed bf16 pairs, zero-padded rows [1433, KPAD)
    for (int idx = tid; idx < KPAD * 8; idx += 256) {
        int k = idx >> 3, c = idx & 7;
        unsigned int u = 0u;
        if (k < IN_FEATS) {
            unsigned int lo = f2bf(W1[k * 16 + 2 * c]);
            unsigned int hi = f2bf(W1[k * 16 + 2 * c + 1]);
            u = lo | (hi << 16);
        }
        Wl[k * WROW + c] = u;
    }
    __syncthreads();

    const int lane = tid & 63;
    const float b1v = b1[lane & 15];
    const int gwave  = blockIdx.x * 4 + (tid >> 6);
    const int nwaves = gridDim.x * 4;

    for (int ch = gwave; ch < N_NODES / 4; ch += nwaves) {
        const int r0 = ch * 4;
        const float* fp = F + (size_t)r0 * IN_FEATS;

        float v[64];                                    // acc[idx = r*16 + j]
        #pragma unroll
        for (int i = 0; i < 64; ++i) v[i] = 0.f;

        // 22 bounds-check-free iterations (k < 1408), unroll 2 for load ILP
        #pragma unroll 2
        for (int i = 0; i < 22; ++i) {
            const int k = i * 64 + lane;
            const float f0 = fp[k];
            const float f1 = fp[IN_FEATS + k];
            const float f2 = fp[2 * IN_FEATS + k];
            const float f3 = fp[3 * IN_FEATS + k];
            float wv[16];
            #pragma unroll
            for (int c = 0; c < 8; ++c) {
                unsigned int u = Wl[k * WROW + c];
                wv[2 * c]     = __uint_as_float(u << 16);
                wv[2 * c + 1] = __uint_as_float(u & 0xffff0000u);
            }
            #pragma unroll
            for (int j = 0; j < 16; ++j) {
                v[j]      += f0 * wv[j];
                v[16 + j] += f1 * wv[j];
                v[32 + j] += f2 * wv[j];
                v[48 + j] += f3 * wv[j];
            }
        }
        {   // masked tail: k = 1408 + lane, active lanes k < 1433
            const int k = 1408 + lane;
            float f0 = 0.f, f1 = 0.f, f2 = 0.f, f3 = 0.f;
            if (k < IN_FEATS) {
                f0 = fp[k];
                f1 = fp[IN_FEATS + k];
                f2 = fp[2 * IN_FEATS + k];
                f3 = fp[3 * IN_FEATS + k];
            }
            float wv[16];
            #pragma unroll
            for (int c = 0; c < 8; ++c) {
                unsigned int u = Wl[k * WROW + c];   // zero-padded up to KPAD
                wv[2 * c]     = __uint_as_float(u << 16);
                wv[2 * c + 1] = __uint_as_float(u & 0xffff0000u);
            }
            #pragma unroll
            for (int j = 0; j < 16; ++j) {
                v[j]      += f0 * wv[j];
                v[16 + j] += f1 * wv[j];
                v[32 + j] += f2 * wv[j];
                v[48 + j] += f3 * wv[j];
            }
        }

        // Halving butterfly: lane l ends with v[0] = full K-sum of idx = l
        #pragma unroll
        for (int d = 5; d >= 0; --d) {
            const int half = 1 << d;
            const bool hi = (lane >> d) & 1;
            #pragma unroll
            for (int t = 0; t < (1 << d); ++t) {
                float sent = hi ? v[t] : v[t + half];
                float recv = __shfl_xor(sent, half, 64);
                float keep = hi ? v[t + half] : v[t];
                v[t] = keep + recv;
            }
        }
        // idx = lane -> row r0 + (lane>>4), col lane&15 -> flat r0*16 + lane
        const size_t off = (size_t)r0 * 16 + lane;
        H[off] = v[0];
        aggbuf[off] = v[0] + b1v;                      // 256B coalesced per wave
    }
}

// Kernel 2: aggbuf[d] += H[s] over edges (layer-1 scatter-add)
__global__ __launch_bounds__(256) void k2_scatter1(
    const int* __restrict__ src, const int* __restrict__ dst,
    const float* __restrict__ H, float* __restrict__ aggbuf)
{
    int t = blockIdx.x * 256 + threadIdx.x;
    int e = t >> 4, j = t & 15;
    if (e < N_EDGES) {
        int s = src[e], d = dst[e];
        atomicAdd(&aggbuf[(size_t)d * 16 + j], H[(size_t)s * 16 + j]);
    }
}

// Kernel 3: x = relu(aggbuf); G = x @ W2; out = G + b2
__global__ __launch_bounds__(256) void k3_layer2(
    const float* __restrict__ aggbuf, const float* __restrict__ W2,
    const float* __restrict__ b2, float* __restrict__ G,
    float* __restrict__ out)
{
    int n = blockIdx.x * 256 + threadIdx.x;
    if (n >= N_NODES) return;
    const float* a = aggbuf + (size_t)n * 16;
    float x[16];
    #pragma unroll
    for (int k = 0; k < 16; ++k) { float vv = a[k]; x[k] = vv > 0.f ? vv : 0.f; }
    #pragma unroll
    for (int j = 0; j < OUT_F; ++j) {
        float g = 0.f;
        #pragma unroll
        for (int k = 0; k < 16; ++k) g += x[k] * W2[k * OUT_F + j];
        G[(size_t)n * OUT_F + j] = g;
        out[(size_t)n * OUT_F + j] = g + b2[j];
    }
}

// Kernel 4: out[d] += G[s] over edges (layer-2 scatter-add)
__global__ __launch_bounds__(256) void k4_scatter2(
    const int* __restrict__ src, const int* __restrict__ dst,
    const float* __restrict__ G, float* __restrict__ out)
{
    int t = blockIdx.x * 256 + threadIdx.x;
    int e = t / OUT_F, j = t % OUT_F;
    if (e < N_EDGES) {
        atomicAdd(&out[(size_t)dst[e] * OUT_F + j], G[(size_t)src[e] * OUT_F + j]);
    }
}

extern "C" void kernel_launch(void* const* d_in, const int* in_sizes, int n_in,
                              void* d_out, int out_size, void* d_ws, size_t ws_size,
                              hipStream_t stream)
{
    const float* F  = (const float*)d_in[0];
    const int*   src = (const int*)d_in[1];
    const int*   dst = (const int*)d_in[2];
    const float* W1 = (const float*)d_in[3];
    const float* b1 = (const float*)d_in[4];
    const float* W2 = (const float*)d_in[5];
    const float* b2 = (const float*)d_in[6];
    float* out = (float*)d_out;

    float* H      = (float*)d_ws;                         // 800,000 f32
    float* aggbuf = H + (size_t)N_NODES * HIDDEN;         // 800,000 f32
    float* G      = H;                                    // reuse H after k2 (dead)

    // k1: 768 blocks = 3 blocks/CU (LDS-capped), per-wave grid-stride
    k1_gemm<<<768, 256, 0, stream>>>(F, W1, b1, H, aggbuf);
    k2_scatter1<<<(N_EDGES * 16) / 256, 256, 0, stream>>>(src, dst, H, aggbuf);
    k3_layer2<<<(N_NODES + 255) / 256, 256, 0, stream>>>(aggbuf, W2, b2, G, out);
    k4_scatter2<<<(N_EDGES * OUT_F + 255) / 256, 256, 0, stream>>>(src, dst, G, out);
}